// Round 8
// baseline (1148.493 us; speedup 1.0000x reference)
//
#include <hip/hip_runtime.h>
#include <hip/hip_bf16.h>

typedef __bf16 bf16_t;
typedef __bf16 bf16x8 __attribute__((ext_vector_type(8)));
typedef __bf16 bf16x4 __attribute__((ext_vector_type(4)));
typedef float f32x4 __attribute__((ext_vector_type(4)));
typedef unsigned long long u64;

#define LNEPS 1e-5f
#define STDEPS 1e-5f

// ---------------- workspace layout (bytes) ----------------
#define PTS_OFF   0UL           // f32 [8*4096*64]          = 8388608
#define IDX_OFF   8519680UL     // i32 [8*4096*16]          = 2097152
#define RED_OFF   10616832UL    // f64 sums[8],sumsq[8] + f32 std[8]
#define STD_OFF   (RED_OFF + 128UL)
#define WP_OFF    10617088UL    // packed bf16 weights      = 1245184
#define POOL1_OFF 11862272UL    // bf16 [32768*256] ; cand4 f32x4[32768] overlays (disjoint lifetime)
#define POOL2_OFF 28639488UL    // u32/f32 [8*256]          = 8192
#define WS_NEED   28647680UL

// ---------------- weight pack: W[Ni][No] f32 -> MFMA frag-contiguous bf16 ----------------
__global__ void k_pack(const float* __restrict__ W, bf16_t* __restrict__ Wp,
                       int No, int sh, int n)
{
  int i = blockIdx.x * 256 + threadIdx.x;
  if (i >= n) return;
  int j = i & 7;
  int l = (i >> 3) & 63;
  int rest = i >> 9;
  int kc = rest & ((1 << sh) - 1);
  int t = rest >> sh;
  int k = kc * 32 + (l >> 4) * 8 + j;
  int col = t * 16 + (l & 15);
  Wp[i] = (bf16_t)W[k * No + col];
}

// ---------------- embedding: pts = relu(LN(x@W_emb+b_emb)); cand4 = [xyz, |xyz|^2] ----------------
__global__ void k_embed(const float* __restrict__ xyz, const float* __restrict__ x,
                        const float* __restrict__ W, const float* __restrict__ bb,
                        const float* __restrict__ g, const float* __restrict__ be,
                        float* __restrict__ pts, float4* __restrict__ cand4)
{
  int p = blockIdx.x * 256 + threadIdx.x;
  float x0 = x[p * 3 + 0], x1 = x[p * 3 + 1], x2 = x[p * 3 + 2];
  float e[64];
  float s = 0.f;
  #pragma unroll
  for (int j = 0; j < 64; ++j) {
    float v = bb[j];
    v = fmaf(x0, W[j], v);
    v = fmaf(x1, W[64 + j], v);
    v = fmaf(x2, W[128 + j], v);
    e[j] = v; s += v;
  }
  float mean = s * (1.f / 64.f);
  float vs = 0.f;
  #pragma unroll
  for (int j = 0; j < 64; ++j) { float d = e[j] - mean; vs = fmaf(d, d, vs); }
  float rstd = rsqrtf(vs * (1.f / 64.f) + LNEPS);
  #pragma unroll
  for (int j = 0; j < 64; ++j)
    pts[p * 64 + j] = fmaxf(0.f, (e[j] - mean) * rstd * g[j] + be[j]);
  float z0 = xyz[p * 3 + 0], z1 = xyz[p * 3 + 1], z2 = xyz[p * 3 + 2];
  cand4[p] = make_float4(z0, z1, z2, z0 * z0 + z1 * z1 + z2 * z2);
}

// ---------------- KNN helpers ----------------
__device__ __forceinline__ void insert16(u64* a, u64 key)
{
  #pragma unroll
  for (int j = 15; j >= 1; --j) {
    u64 lo = (key < a[j - 1]) ? a[j - 1] : key;
    a[j] = (key < a[j]) ? lo : a[j];
  }
  a[0] = (key < a[0]) ? key : a[0];
}

__device__ __forceinline__ void merge16(u64* a, const u64* b)
{
  u64 m[16];
  #pragma unroll
  for (int i = 0; i < 16; ++i) m[i] = (a[i] < b[15 - i]) ? a[i] : b[15 - i];
  #pragma unroll
  for (int d = 8; d >= 1; d >>= 1) {
    #pragma unroll
    for (int i = 0; i < 16; ++i) {
      if ((i & d) == 0) {
        u64 xv = m[i], yv = m[i + d];
        bool c = yv < xv;
        m[i] = c ? yv : xv;
        m[i + d] = c ? xv : yv;
      }
    }
  }
  #pragma unroll
  for (int i = 0; i < 16; ++i) a[i] = m[i];
}

__global__ __launch_bounds__(256) void k_knn(const float4* __restrict__ cand4,
                                             int* __restrict__ idx)
{
  __shared__ u64 ldsB[256 * 17];
  const int tid = threadIdx.x;
  const int l = tid & 63;
  const int w = tid >> 6;
  const int wu = __builtin_amdgcn_readfirstlane(w);
  const int b = blockIdx.x >> 6;
  const int g = blockIdx.x & 63;
  const int p = (b << 12) + (g << 6) + l;
  const float4 q = cand4[p];
  const float4* __restrict__ cbase = cand4 + (b << 12) + (wu << 10);
  const int mbase = wu << 10;
  u64 arr[16];
  const u64 KINF = ((u64)0x7F800000u << 32) | 0xFFFFFFFFu;
  #pragma unroll
  for (int j = 0; j < 16; ++j) arr[j] = KINF;
  float tf = 3.4e38f;
  int cnt = 0;
  u64* myb = &ldsB[tid * 17];

  for (int m0 = 0; m0 < 1024; m0 += 8) {
    if (__any(cnt > 8)) {
      for (int j2 = 0; j2 < cnt; ++j2) insert16(arr, myb[j2]);
      cnt = 0;
      tf = __uint_as_float((unsigned)(arr[15] >> 32));
    }
    #pragma unroll
    for (int u = 0; u < 8; ++u) {
      float4 c = cbase[m0 + u];
      float dot = q.x * c.x;
      dot = fmaf(q.y, c.y, dot);
      dot = fmaf(q.z, c.z, dot);
      float d = fmaxf(fmaf(-2.f, dot, q.w + c.w), 0.f);
      if (d < tf) {
        myb[cnt] = ((u64)__float_as_uint(d) << 32) | (unsigned)(mbase + m0 + u);
        ++cnt;
      }
    }
  }
  for (int j2 = 0; j2 < cnt; ++j2) insert16(arr, myb[j2]);

  #pragma unroll
  for (int j = 0; j < 16; ++j) myb[j] = arr[j];
  __syncthreads();
  if ((w & 1) == 0) {
    u64 brr[16];
    #pragma unroll
    for (int j = 0; j < 16; ++j) brr[j] = ldsB[((w + 1) * 64 + l) * 17 + j];
    merge16(arr, brr);
    #pragma unroll
    for (int j = 0; j < 16; ++j) myb[j] = arr[j];
  }
  __syncthreads();
  if (w == 0) {
    u64 brr[16];
    #pragma unroll
    for (int j = 0; j < 16; ++j) brr[j] = ldsB[(2 * 64 + l) * 17 + j];
    merge16(arr, brr);
    #pragma unroll
    for (int j = 0; j < 16; ++j) idx[p * 16 + j] = (int)(unsigned)(arr[j] & 0xFFFFFFFFu);
  }
}

// ---------------- std reduction over diff = pts[idx] - pts (per batch) ----------------
__global__ void k_stdred(const float* __restrict__ pts, const int* __restrict__ idx,
                         double* __restrict__ red)
{
  int b = blockIdx.x >> 6, chunk = blockIdx.x & 63;
  int tid = threadIdx.x;
  int h = tid & 63;
  int r0 = chunk * 1024 + (tid >> 6);
  float s = 0.f, s2 = 0.f;
  for (int i = 0; i < 256; ++i) {
    int row = r0 + 4 * i;
    int n = row >> 4, k = row & 15;
    int ni = idx[((b << 12) + n) * 16 + k];
    float v = pts[((b << 12) + ni) * 64 + h] - pts[((b << 12) + n) * 64 + h];
    s += v; s2 = fmaf(v, v, s2);
  }
  double ds = (double)s, ds2 = (double)s2;
  #pragma unroll
  for (int m = 1; m < 64; m <<= 1) {
    ds += __shfl_xor(ds, m, 64);
    ds2 += __shfl_xor(ds2, m, 64);
  }
  __shared__ double sred[8];
  int w = tid >> 6;
  if ((tid & 63) == 0) { sred[w] = ds; sred[4 + w] = ds2; }
  __syncthreads();
  if (tid == 0) {
    atomicAdd(&red[b], sred[0] + sred[1] + sred[2] + sred[3]);
    atomicAdd(&red[8 + b], sred[4] + sred[5] + sred[6] + sred[7]);
  }
}

__global__ void k_stdfin(const double* __restrict__ red, float* __restrict__ stdv)
{
  int t = threadIdx.x;
  if (t < 8) {
    double M = 4194304.0;
    double s = red[t], s2 = red[8 + t];
    double var = (s2 - s * s / M) / (M - 1.0);
    stdv[t] = (float)sqrt(var);
  }
}

// ---------------- MLP helpers (swapped-operand MFMA: D[outcol][datarow]) ----------------
__device__ __forceinline__ bf16x4 cvt4(f32x4 v)
{
  bf16x4 o;
  o[0] = (bf16_t)v[0]; o[1] = (bf16_t)v[1]; o[2] = (bf16_t)v[2]; o[3] = (bf16_t)v[3];
  return o;
}

__device__ __forceinline__ f32x4 shflmax(f32x4 v, int m)
{
  f32x4 r;
  #pragma unroll
  for (int c = 0; c < 4; ++c) r[c] = fmaxf(v[c], __shfl_xor(v[c], m, 64));
  return r;
}

// GEMM over col-tiles t0..t0+NTW-1, all 4 row-tiles (64 rows).
template <int NKC, int NTW>
__device__ __forceinline__ void gemm_sw(const bf16_t* __restrict__ inS, const int instride,
                                        const bf16_t* __restrict__ Wp,
                                        const int t0, const int l, f32x4 (*acc)[4])
{
  const int lr = l & 15, lg = l >> 4;
  const bf16x8* __restrict__ Wf = (const bf16x8*)Wp;
  #pragma unroll
  for (int kc = 0; kc < NKC; ++kc) {
    bf16x8 af[4];
    #pragma unroll
    for (int rt = 0; rt < 4; ++rt)
      af[rt] = *(const bf16x8*)(inS + (rt * 16 + lr) * instride + kc * 32 + lg * 8);
    #pragma unroll
    for (int ct = 0; ct < NTW; ++ct) {
      bf16x8 bw = Wf[((t0 + ct) * NKC + kc) * 64 + l];
      #pragma unroll
      for (int rt = 0; rt < 4; ++rt)
        acc[ct][rt] = __builtin_amdgcn_mfma_f32_16x16x32_bf16(bw, af[rt], acc[ct][rt], 0, 0, 0);
    }
  }
}

// add bias in-place, accumulate per-row-tile partial sums into sm/sq (regs)
template <int NTW>
__device__ __forceinline__ void add_bias_acc(f32x4 (*acc)[4], const float* __restrict__ bias,
                                             const int t0, const int lg,
                                             float* sm, float* sq)
{
  #pragma unroll
  for (int ct = 0; ct < NTW; ++ct) {
    f32x4 b4 = *(const f32x4*)(bias + (t0 + ct) * 16 + 4 * lg);
    #pragma unroll
    for (int rt = 0; rt < 4; ++rt) {
      f32x4 v = acc[ct][rt] + b4;
      acc[ct][rt] = v;
      #pragma unroll
      for (int rg = 0; rg < 4; ++rg) { sm[rt] += v[rg]; sq[rt] = fmaf(v[rg], v[rg], sq[rt]); }
    }
  }
}

// lg-axis shuffle reduce + per-wave partial store (16 waves)
__device__ __forceinline__ void stats_store(float* sm, float* sq, const int w, const int l,
                                            float* __restrict__ smP, float* __restrict__ sqP)
{
  const int lr = l & 15, lg = l >> 4;
  #pragma unroll
  for (int rt = 0; rt < 4; ++rt) {
    sm[rt] += __shfl_xor(sm[rt], 16, 64); sq[rt] += __shfl_xor(sq[rt], 16, 64);
    sm[rt] += __shfl_xor(sm[rt], 32, 64); sq[rt] += __shfl_xor(sq[rt], 32, 64);
  }
  if (lg == 0) {
    #pragma unroll
    for (int rt = 0; rt < 4; ++rt) {
      smP[w * 64 + rt * 16 + lr] = sm[rt];
      sqP[w * 64 + rt * 16 + lr] = sq[rt];
    }
  }
}

__device__ __forceinline__ void mean_rstd(const float* __restrict__ smP,
                                          const float* __restrict__ sqP,
                                          const int lr, const float invNC,
                                          float* mean, float* rstd)
{
  #pragma unroll
  for (int rt = 0; rt < 4; ++rt) {
    int row = rt * 16 + lr;
    float s = 0.f, q = 0.f;
    #pragma unroll
    for (int u = 0; u < 16; ++u) { s += smP[u * 64 + row]; q += sqP[u * 64 + row]; }
    float me = s * invNC;
    float var = q * invNC - me * me;
    mean[rt] = me; rstd[rt] = rsqrtf(var + LNEPS);
  }
}

// ---------------- fused 3-layer MLP block ----------------
// 64 rows/block, 1024 threads = 16 waves, 16-way column split (1/2/1 tiles per wave).
// Per-lane peak live set: L2 acc 32 + af 16 + residb 8 + stats/misc ~35 => fits the
// 128-reg unified VGPR+AGPR budget at 4 waves/EU -> no scratch spill (R4-R7's
// 360-460MB WRITE_SIZE was spill: 8-wave layout needed 64 acc regs/lane).
template <int NKCIN, int INSTRIDE, int REGEL, bool KPOOL>
__global__ __launch_bounds__(1024, 4) void k_mlp(
    const float* __restrict__ pts, const int* __restrict__ idxp,
    const float* __restrict__ stdv, const float* __restrict__ alpha,
    const float* __restrict__ beta, const bf16_t* __restrict__ pooled1_in,
    const bf16_t* __restrict__ Wp0, const float* __restrict__ b0,
    const float* __restrict__ g0, const float* __restrict__ be0,
    const bf16_t* __restrict__ Wp1, const float* __restrict__ b1,
    const float* __restrict__ g1, const float* __restrict__ be1,
    const bf16_t* __restrict__ Wp2, const float* __restrict__ b2,
    const float* __restrict__ g2, const float* __restrict__ be2,
    bf16_t* __restrict__ pooled1_out, unsigned* __restrict__ pooled2)
{
  __shared__ bf16_t region[REGEL];
  __shared__ float smP[16 * 64];
  __shared__ float sqP[16 * 64];
  bf16_t* inS = region;                     // [64][INSTRIDE]; dead after L1 gemm
  bf16_t* yS = region + 64 * INSTRIDE;      // [64][264]
  bf16_t* hS = region;                      // [64][520], overlays after L2 reads done

  const int tid = threadIdx.x;
  const int l = tid & 63, w = tid >> 6;     // 16 waves
  const int lr = l & 15, lg = l >> 4;
  const int p0 = blockIdx.x * (KPOOL ? 4 : 64);
  const int bb = p0 >> 12;

  // ---- stage input rows (64 rows; 16 col-chunks of 8) ----
  {
    const int r = tid >> 4, q = tid & 15;
    if (KPOOL) {
      const float inv = 1.0f / (stdv[bb] + STDEPS);
      const int p = p0 + (r >> 4), k = r & 15;
      if (q < 8) {
        const int ni = idxp[p * 16 + k];
        const float* sn = pts + ((size_t)(bb << 12) + ni) * 64 + q * 8;
        const float* sp = pts + (size_t)p * 64 + q * 8;
        #pragma unroll
        for (int i = 0; i < 2; ++i) {
          f32x4 a = *(const f32x4*)(sn + 4 * i);
          f32x4 c = *(const f32x4*)(sp + 4 * i);
          f32x4 av = *(const f32x4*)(alpha + q * 8 + 4 * i);
          f32x4 bv = *(const f32x4*)(beta + q * 8 + 4 * i);
          f32x4 v = (a - c) * (av * inv) + bv;
          *(bf16x4*)(inS + r * INSTRIDE + q * 8 + 4 * i) = cvt4(v);
        }
      } else {
        const int qq = q - 8;
        const float* sp = pts + (size_t)p * 64 + qq * 8;
        #pragma unroll
        for (int i = 0; i < 2; ++i) {
          f32x4 c = *(const f32x4*)(sp + 4 * i);
          *(bf16x4*)(inS + r * INSTRIDE + 64 + qq * 8 + 4 * i) = cvt4(c);
        }
      }
    } else {
      #pragma unroll
      for (int j = 0; j < 2; ++j) {
        *(bf16x8*)(inS + r * INSTRIDE + q * 16 + j * 8) =
            *(const bf16x8*)(pooled1_in + (size_t)(p0 + r) * 256 + q * 16 + j * 8);
      }
    }
  }
  __syncthreads();

  bf16x4 residb[4];                          // LN1 output tile w, bf16
  float mean[4], rstd[4];

  // ---- L1: IN -> 256, LN (no relu); tile w ----
  {
    f32x4 acc[1][4];
    #pragma unroll
    for (int rt = 0; rt < 4; ++rt) acc[0][rt] = {0.f, 0.f, 0.f, 0.f};
    gemm_sw<NKCIN, 1>(inS, INSTRIDE, Wp0, w, l, acc);
    float sm[4] = {0.f, 0.f, 0.f, 0.f}, sq[4] = {0.f, 0.f, 0.f, 0.f};
    add_bias_acc<1>(acc, b0, w, lg, sm, sq);
    stats_store(sm, sq, w, l, smP, sqP);
    __syncthreads();
    mean_rstd(smP, sqP, lr, 1.f / 256.f, mean, rstd);
    {
      f32x4 g4 = *(const f32x4*)(g0 + w * 16 + 4 * lg);
      f32x4 be4 = *(const f32x4*)(be0 + w * 16 + 4 * lg);
      #pragma unroll
      for (int rt = 0; rt < 4; ++rt) {
        f32x4 v;
        #pragma unroll
        for (int rg = 0; rg < 4; ++rg)
          v[rg] = (acc[0][rt][rg] - mean[rt]) * rstd[rt] * g4[rg] + be4[rg];
        bf16x4 vb = cvt4(v);
        residb[rt] = vb;
        *(bf16x4*)(yS + (rt * 16 + lr) * 264 + w * 16 + 4 * lg) = vb;
      }
    }
  }
  __syncthreads();   // inS dead; yS live for L2

  // ---- L2: 256 -> 512, LN + relu; tiles w*2, w*2+1 ----
  {
    f32x4 acc[2][4];
    #pragma unroll
    for (int ct = 0; ct < 2; ++ct)
      #pragma unroll
      for (int rt = 0; rt < 4; ++rt) acc[ct][rt] = {0.f, 0.f, 0.f, 0.f};
    gemm_sw<8, 2>(yS, 264, Wp1, w * 2, l, acc);
    float sm[4] = {0.f, 0.f, 0.f, 0.f}, sq[4] = {0.f, 0.f, 0.f, 0.f};
    add_bias_acc<2>(acc, b1, w * 2, lg, sm, sq);
    stats_store(sm, sq, w, l, smP, sqP);
    __syncthreads();   // stats ready; all yS reads done -> hS may overlay
    mean_rstd(smP, sqP, lr, 1.f / 512.f, mean, rstd);
    #pragma unroll
    for (int ct = 0; ct < 2; ++ct) {
      const int t = w * 2 + ct;
      f32x4 g4 = *(const f32x4*)(g1 + t * 16 + 4 * lg);
      f32x4 be4 = *(const f32x4*)(be1 + t * 16 + 4 * lg);
      #pragma unroll
      for (int rt = 0; rt < 4; ++rt) {
        f32x4 v;
        #pragma unroll
        for (int rg = 0; rg < 4; ++rg)
          v[rg] = fmaxf(0.f, (acc[ct][rt][rg] - mean[rt]) * rstd[rt] * g4[rg] + be4[rg]);
        *(bf16x4*)(hS + (rt * 16 + lr) * 520 + t * 16 + 4 * lg) = cvt4(v);
      }
    }
  }
  __syncthreads();

  // ---- L3: 512 -> 256, resid + LN + relu, pool; tile w ----
  {
    f32x4 acc[1][4];
    #pragma unroll
    for (int rt = 0; rt < 4; ++rt) acc[0][rt] = {0.f, 0.f, 0.f, 0.f};
    gemm_sw<16, 1>(hS, 520, Wp2, w, l, acc);
    float sm[4] = {0.f, 0.f, 0.f, 0.f}, sq[4] = {0.f, 0.f, 0.f, 0.f};
    add_bias_acc<1>(acc, b2, w, lg, sm, sq);
    stats_store(sm, sq, w, l, smP, sqP);
    __syncthreads();
    mean_rstd(smP, sqP, lr, 1.f / 256.f, mean, rstd);
    {
      f32x4 g4 = *(const f32x4*)(g2 + w * 16 + 4 * lg);
      f32x4 be4 = *(const f32x4*)(be2 + w * 16 + 4 * lg);
      f32x4 mv = {0.f, 0.f, 0.f, 0.f};
      #pragma unroll
      for (int rt = 0; rt < 4; ++rt) {
        f32x4 v;
        #pragma unroll
        for (int rg = 0; rg < 4; ++rg)
          v[rg] = fmaxf(0.f, (float)residb[rt][rg] +
                             (acc[0][rt][rg] - mean[rt]) * rstd[rt] * g4[rg] + be4[rg]);
        if (KPOOL) {
          v = shflmax(v, 1); v = shflmax(v, 2); v = shflmax(v, 4); v = shflmax(v, 8);
          if (lr == 0)
            *(bf16x4*)(pooled1_out + (size_t)(p0 + rt) * 256 + w * 16 + 4 * lg) = cvt4(v);
        } else {
          #pragma unroll
          for (int rg = 0; rg < 4; ++rg) mv[rg] = fmaxf(mv[rg], v[rg]);
        }
      }
      if (!KPOOL) {
        mv = shflmax(mv, 1); mv = shflmax(mv, 2); mv = shflmax(mv, 4); mv = shflmax(mv, 8);
        if (lr == 0) {
          #pragma unroll
          for (int rg = 0; rg < 4; ++rg)
            atomicMax(&pooled2[bb * 256 + w * 16 + 4 * lg + rg], __float_as_uint(mv[rg]));
        }
      }
    }
  }
}

// ---------------- final head ----------------
__global__ void k_final(const unsigned* __restrict__ pooled2,
                        const float* __restrict__ W, const float* __restrict__ bb,
                        const float* __restrict__ g, const float* __restrict__ be,
                        float* __restrict__ out)
{
  int w = threadIdx.x >> 6;
  int l = threadIdx.x & 63;
  float acc = bb[l];
  for (int k = 0; k < 256; ++k)
    acc = fmaf(__uint_as_float(pooled2[w * 256 + k]), W[k * 64 + l], acc);
  float sm = acc, sq = acc * acc;
  #pragma unroll
  for (int m = 1; m < 64; m <<= 1) {
    sm += __shfl_xor(sm, m, 64);
    sq += __shfl_xor(sq, m, 64);
  }
  float mean = sm * (1.f / 64.f);
  float var = sq * (1.f / 64.f) - mean * mean;
  out[w * 64 + l] = (acc - mean) * rsqrtf(var + LNEPS) * g[l] + be[l];
}

// ---------------- launch ----------------
extern "C" void kernel_launch(void* const* d_in, const int* in_sizes, int n_in,
                              void* d_out, int out_size, void* d_ws, size_t ws_size,
                              hipStream_t stream)
{
  if (ws_size < WS_NEED) return;
  const float* xyz = (const float*)d_in[0];
  const float* x = (const float*)d_in[1];
  const float* W_emb = (const float*)d_in[2];
  const float* b_emb = (const float*)d_in[3];
  const float* g_emb = (const float*)d_in[4];
  const float* be_emb = (const float*)d_in[5];
  const float* alpha = (const float*)d_in[6];
  const float* beta = (const float*)d_in[7];
  const float* W_pre = (const float*)d_in[8];
  const float* b_pre = (const float*)d_in[9];
  const float* g_pre = (const float*)d_in[10];
  const float* be_pre = (const float*)d_in[11];
  const float* W1a = (const float*)d_in[12];
  const float* b1a = (const float*)d_in[13];
  const float* g1a = (const float*)d_in[14];
  const float* be1a = (const float*)d_in[15];
  const float* W2a = (const float*)d_in[16];
  const float* b2a = (const float*)d_in[17];
  const float* g2a = (const float*)d_in[18];
  const float* be2a = (const float*)d_in[19];
  const float* W_pos = (const float*)d_in[20];
  const float* b_pos = (const float*)d_in[21];
  const float* g_pos = (const float*)d_in[22];
  const float* be_pos = (const float*)d_in[23];
  const float* W1b = (const float*)d_in[24];
  const float* b1b = (const float*)d_in[25];
  const float* g1b = (const float*)d_in[26];
  const float* be1b = (const float*)d_in[27];
  const float* W2b = (const float*)d_in[28];
  const float* b2b = (const float*)d_in[29];
  const float* g2b = (const float*)d_in[30];
  const float* be2b = (const float*)d_in[31];
  const float* W_fin = (const float*)d_in[32];
  const float* b_fin = (const float*)d_in[33];
  const float* g_fin = (const float*)d_in[34];
  const float* be_fin = (const float*)d_in[35];

  char* ws = (char*)d_ws;
  float* pts = (float*)(ws + PTS_OFF);
  int* idx = (int*)(ws + IDX_OFF);
  double* red = (double*)(ws + RED_OFF);
  float* stdv = (float*)(ws + STD_OFF);
  bf16_t* WpPre = (bf16_t*)(ws + WP_OFF);
  bf16_t* Wp1a = WpPre + 32768;
  bf16_t* Wp2a = Wp1a + 131072;
  bf16_t* WpPos = Wp2a + 131072;
  bf16_t* Wp1b = WpPos + 65536;
  bf16_t* Wp2b = Wp1b + 131072;
  bf16_t* pooled1 = (bf16_t*)(ws + POOL1_OFF);
  float4* cand4 = (float4*)(ws + POOL1_OFF);   // overlays pooled1; disjoint lifetime
  unsigned* pooled2 = (unsigned*)(ws + POOL2_OFF);

  hipMemsetAsync(ws + RED_OFF, 0, 256, stream);
  hipMemsetAsync(ws + POOL2_OFF, 0, 8192, stream);

  k_pack<<<32768 / 256, 256, 0, stream>>>(W_pre, WpPre, 256, 2, 32768);
  k_pack<<<131072 / 256, 256, 0, stream>>>(W1a, Wp1a, 512, 3, 131072);
  k_pack<<<131072 / 256, 256, 0, stream>>>(W2a, Wp2a, 256, 4, 131072);
  k_pack<<<65536 / 256, 256, 0, stream>>>(W_pos, WpPos, 256, 3, 65536);
  k_pack<<<131072 / 256, 256, 0, stream>>>(W1b, Wp1b, 512, 3, 131072);
  k_pack<<<131072 / 256, 256, 0, stream>>>(W2b, Wp2b, 256, 4, 131072);

  k_embed<<<32768 / 256, 256, 0, stream>>>(xyz, x, W_emb, b_emb, g_emb, be_emb, pts, cand4);
  k_knn<<<512, 256, 0, stream>>>(cand4, idx);
  k_stdred<<<512, 256, 0, stream>>>(pts, idx, red);
  k_stdfin<<<1, 64, 0, stream>>>(red, stdv);

  k_mlp<4, 136, 33280, true><<<8192, 1024, 0, stream>>>(
      pts, idx, stdv, alpha, beta, nullptr,
      WpPre, b_pre, g_pre, be_pre,
      Wp1a, b1a, g1a, be1a,
      Wp2a, b2a, g2a, be2a,
      pooled1, nullptr);
  k_mlp<8, 264, 33792, false><<<512, 1024, 0, stream>>>(
      nullptr, nullptr, nullptr, nullptr, nullptr, pooled1,
      WpPos, b_pos, g_pos, be_pos,
      Wp1b, b1b, g1b, be1b,
      Wp2b, b2b, g2b, be2b,
      nullptr, pooled2);
  k_final<<<1, 512, 0, stream>>>(pooled2, W_fin, b_fin, g_fin, be_fin, (float*)d_out);
}

// Round 9
// 947.837 us; speedup vs baseline: 1.2117x; 1.2117x over previous
//
#include <hip/hip_runtime.h>
#include <hip/hip_bf16.h>

typedef __bf16 bf16_t;
typedef __bf16 bf16x8 __attribute__((ext_vector_type(8)));
typedef __bf16 bf16x4 __attribute__((ext_vector_type(4)));
typedef float f32x4 __attribute__((ext_vector_type(4)));
typedef unsigned long long u64;

#define LNEPS 1e-5f
#define STDEPS 1e-5f

// ---------------- workspace layout (bytes) ----------------
#define PTS_OFF   0UL           // f32 [8*4096*64]          = 8388608
#define IDX_OFF   8519680UL     // i32 [8*4096*16]          = 2097152
#define RED_OFF   10616832UL    // f64 sums[8],sumsq[8] + f32 std[8]
#define STD_OFF   (RED_OFF + 128UL)
#define WP_OFF    10617088UL    // packed bf16 weights      = 1245184
#define POOL1_OFF 11862272UL    // bf16 [32768*256] ; cand4 f32x4[32768] overlays (disjoint lifetime)
#define POOL2_OFF 28639488UL    // u32/f32 [8*256]          = 8192
#define WS_NEED   28647680UL

// ---------------- weight pack: W[Ni][No] f32 -> MFMA frag-contiguous bf16 ----------------
__global__ void k_pack(const float* __restrict__ W, bf16_t* __restrict__ Wp,
                       int No, int sh, int n)
{
  int i = blockIdx.x * 256 + threadIdx.x;
  if (i >= n) return;
  int j = i & 7;
  int l = (i >> 3) & 63;
  int rest = i >> 9;
  int kc = rest & ((1 << sh) - 1);
  int t = rest >> sh;
  int k = kc * 32 + (l >> 4) * 8 + j;
  int col = t * 16 + (l & 15);
  Wp[i] = (bf16_t)W[k * No + col];
}

// ---------------- embedding: pts = relu(LN(x@W_emb+b_emb)); cand4 = [xyz, |xyz|^2] ----------------
__global__ void k_embed(const float* __restrict__ xyz, const float* __restrict__ x,
                        const float* __restrict__ W, const float* __restrict__ bb,
                        const float* __restrict__ g, const float* __restrict__ be,
                        float* __restrict__ pts, float4* __restrict__ cand4)
{
  int p = blockIdx.x * 256 + threadIdx.x;
  float x0 = x[p * 3 + 0], x1 = x[p * 3 + 1], x2 = x[p * 3 + 2];
  float e[64];
  float s = 0.f;
  #pragma unroll
  for (int j = 0; j < 64; ++j) {
    float v = bb[j];
    v = fmaf(x0, W[j], v);
    v = fmaf(x1, W[64 + j], v);
    v = fmaf(x2, W[128 + j], v);
    e[j] = v; s += v;
  }
  float mean = s * (1.f / 64.f);
  float vs = 0.f;
  #pragma unroll
  for (int j = 0; j < 64; ++j) { float d = e[j] - mean; vs = fmaf(d, d, vs); }
  float rstd = rsqrtf(vs * (1.f / 64.f) + LNEPS);
  #pragma unroll
  for (int j = 0; j < 64; ++j)
    pts[p * 64 + j] = fmaxf(0.f, (e[j] - mean) * rstd * g[j] + be[j]);
  float z0 = xyz[p * 3 + 0], z1 = xyz[p * 3 + 1], z2 = xyz[p * 3 + 2];
  cand4[p] = make_float4(z0, z1, z2, z0 * z0 + z1 * z1 + z2 * z2);
}

// ---------------- KNN helpers ----------------
__device__ __forceinline__ void insert16(u64* a, u64 key)
{
  #pragma unroll
  for (int j = 15; j >= 1; --j) {
    u64 lo = (key < a[j - 1]) ? a[j - 1] : key;
    a[j] = (key < a[j]) ? lo : a[j];
  }
  a[0] = (key < a[0]) ? key : a[0];
}

__device__ __forceinline__ void merge16(u64* a, const u64* b)
{
  u64 m[16];
  #pragma unroll
  for (int i = 0; i < 16; ++i) m[i] = (a[i] < b[15 - i]) ? a[i] : b[15 - i];
  #pragma unroll
  for (int d = 8; d >= 1; d >>= 1) {
    #pragma unroll
    for (int i = 0; i < 16; ++i) {
      if ((i & d) == 0) {
        u64 xv = m[i], yv = m[i + d];
        bool c = yv < xv;
        m[i] = c ? yv : xv;
        m[i + d] = c ? xv : yv;
      }
    }
  }
  #pragma unroll
  for (int i = 0; i < 16; ++i) a[i] = m[i];
}

__global__ __launch_bounds__(256) void k_knn(const float4* __restrict__ cand4,
                                             int* __restrict__ idx)
{
  __shared__ u64 ldsB[256 * 17];
  const int tid = threadIdx.x;
  const int l = tid & 63;
  const int w = tid >> 6;
  const int wu = __builtin_amdgcn_readfirstlane(w);
  const int b = blockIdx.x >> 6;
  const int g = blockIdx.x & 63;
  const int p = (b << 12) + (g << 6) + l;
  const float4 q = cand4[p];
  const float4* __restrict__ cbase = cand4 + (b << 12) + (wu << 10);
  const int mbase = wu << 10;
  u64 arr[16];
  const u64 KINF = ((u64)0x7F800000u << 32) | 0xFFFFFFFFu;
  #pragma unroll
  for (int j = 0; j < 16; ++j) arr[j] = KINF;
  float tf = 3.4e38f;
  int cnt = 0;
  u64* myb = &ldsB[tid * 17];

  for (int m0 = 0; m0 < 1024; m0 += 8) {
    if (__any(cnt > 8)) {
      for (int j2 = 0; j2 < cnt; ++j2) insert16(arr, myb[j2]);
      cnt = 0;
      tf = __uint_as_float((unsigned)(arr[15] >> 32));
    }
    #pragma unroll
    for (int u = 0; u < 8; ++u) {
      float4 c = cbase[m0 + u];
      float dot = q.x * c.x;
      dot = fmaf(q.y, c.y, dot);
      dot = fmaf(q.z, c.z, dot);
      float d = fmaxf(fmaf(-2.f, dot, q.w + c.w), 0.f);
      if (d < tf) {
        myb[cnt] = ((u64)__float_as_uint(d) << 32) | (unsigned)(mbase + m0 + u);
        ++cnt;
      }
    }
  }
  for (int j2 = 0; j2 < cnt; ++j2) insert16(arr, myb[j2]);

  #pragma unroll
  for (int j = 0; j < 16; ++j) myb[j] = arr[j];
  __syncthreads();
  if ((w & 1) == 0) {
    u64 brr[16];
    #pragma unroll
    for (int j = 0; j < 16; ++j) brr[j] = ldsB[((w + 1) * 64 + l) * 17 + j];
    merge16(arr, brr);
    #pragma unroll
    for (int j = 0; j < 16; ++j) myb[j] = arr[j];
  }
  __syncthreads();
  if (w == 0) {
    u64 brr[16];
    #pragma unroll
    for (int j = 0; j < 16; ++j) brr[j] = ldsB[(2 * 64 + l) * 17 + j];
    merge16(arr, brr);
    #pragma unroll
    for (int j = 0; j < 16; ++j) idx[p * 16 + j] = (int)(unsigned)(arr[j] & 0xFFFFFFFFu);
  }
}

// ---------------- std reduction over diff = pts[idx] - pts (per batch) ----------------
__global__ void k_stdred(const float* __restrict__ pts, const int* __restrict__ idx,
                         double* __restrict__ red)
{
  int b = blockIdx.x >> 6, chunk = blockIdx.x & 63;
  int tid = threadIdx.x;
  int h = tid & 63;
  int r0 = chunk * 1024 + (tid >> 6);
  float s = 0.f, s2 = 0.f;
  for (int i = 0; i < 256; ++i) {
    int row = r0 + 4 * i;
    int n = row >> 4, k = row & 15;
    int ni = idx[((b << 12) + n) * 16 + k];
    float v = pts[((b << 12) + ni) * 64 + h] - pts[((b << 12) + n) * 64 + h];
    s += v; s2 = fmaf(v, v, s2);
  }
  double ds = (double)s, ds2 = (double)s2;
  #pragma unroll
  for (int m = 1; m < 64; m <<= 1) {
    ds += __shfl_xor(ds, m, 64);
    ds2 += __shfl_xor(ds2, m, 64);
  }
  __shared__ double sred[8];
  int w = tid >> 6;
  if ((tid & 63) == 0) { sred[w] = ds; sred[4 + w] = ds2; }
  __syncthreads();
  if (tid == 0) {
    atomicAdd(&red[b], sred[0] + sred[1] + sred[2] + sred[3]);
    atomicAdd(&red[8 + b], sred[4] + sred[5] + sred[6] + sred[7]);
  }
}

__global__ void k_stdfin(const double* __restrict__ red, float* __restrict__ stdv)
{
  int t = threadIdx.x;
  if (t < 8) {
    double M = 4194304.0;
    double s = red[t], s2 = red[8 + t];
    double var = (s2 - s * s / M) / (M - 1.0);
    stdv[t] = (float)sqrt(var);
  }
}

// ---------------- MLP helpers (swapped-operand MFMA: D[outcol][datarow]) ----------------
__device__ __forceinline__ bf16x4 cvt4(f32x4 v)
{
  bf16x4 o;
  o[0] = (bf16_t)v[0]; o[1] = (bf16_t)v[1]; o[2] = (bf16_t)v[2]; o[3] = (bf16_t)v[3];
  return o;
}

__device__ __forceinline__ f32x4 shflmax(f32x4 v, int m)
{
  f32x4 r;
  #pragma unroll
  for (int c = 0; c < 4; ++c) r[c] = fmaxf(v[c], __shfl_xor(v[c], m, 64));
  return r;
}

// GEMM over col-tiles t0..t0+NTW-1, all 4 row-tiles (64 rows).
template <int NKC, int NTW>
__device__ __forceinline__ void gemm_sw(const bf16_t* __restrict__ inS, const int instride,
                                        const bf16_t* __restrict__ Wp,
                                        const int t0, const int l, f32x4 (*acc)[4])
{
  const int lr = l & 15, lg = l >> 4;
  const bf16x8* __restrict__ Wf = (const bf16x8*)Wp;
  #pragma unroll
  for (int kc = 0; kc < NKC; ++kc) {
    bf16x8 af[4];
    #pragma unroll
    for (int rt = 0; rt < 4; ++rt)
      af[rt] = *(const bf16x8*)(inS + (rt * 16 + lr) * instride + kc * 32 + lg * 8);
    #pragma unroll
    for (int ct = 0; ct < NTW; ++ct) {
      bf16x8 bw = Wf[((t0 + ct) * NKC + kc) * 64 + l];
      #pragma unroll
      for (int rt = 0; rt < 4; ++rt)
        acc[ct][rt] = __builtin_amdgcn_mfma_f32_16x16x32_bf16(bw, af[rt], acc[ct][rt], 0, 0, 0);
    }
  }
}

// add bias in-place, accumulate per-row-tile partial sums into sm/sq (regs)
template <int NTW>
__device__ __forceinline__ void add_bias_acc(f32x4 (*acc)[4], const float* __restrict__ bias,
                                             const int t0, const int lg,
                                             float* sm, float* sq)
{
  #pragma unroll
  for (int ct = 0; ct < NTW; ++ct) {
    f32x4 b4 = *(const f32x4*)(bias + (t0 + ct) * 16 + 4 * lg);
    #pragma unroll
    for (int rt = 0; rt < 4; ++rt) {
      f32x4 v = acc[ct][rt] + b4;
      acc[ct][rt] = v;
      #pragma unroll
      for (int rg = 0; rg < 4; ++rg) { sm[rt] += v[rg]; sq[rt] = fmaf(v[rg], v[rg], sq[rt]); }
    }
  }
}

// lg-axis shuffle reduce + per-wave partial store (8 waves)
__device__ __forceinline__ void stats_store(float* sm, float* sq, const int w, const int l,
                                            float* __restrict__ smP, float* __restrict__ sqP)
{
  const int lr = l & 15, lg = l >> 4;
  #pragma unroll
  for (int rt = 0; rt < 4; ++rt) {
    sm[rt] += __shfl_xor(sm[rt], 16, 64); sq[rt] += __shfl_xor(sq[rt], 16, 64);
    sm[rt] += __shfl_xor(sm[rt], 32, 64); sq[rt] += __shfl_xor(sq[rt], 32, 64);
  }
  if (lg == 0) {
    #pragma unroll
    for (int rt = 0; rt < 4; ++rt) {
      smP[w * 64 + rt * 16 + lr] = sm[rt];
      sqP[w * 64 + rt * 16 + lr] = sq[rt];
    }
  }
}

__device__ __forceinline__ void mean_rstd(const float* __restrict__ smP,
                                          const float* __restrict__ sqP,
                                          const int lr, const float invNC,
                                          float* mean, float* rstd)
{
  #pragma unroll
  for (int rt = 0; rt < 4; ++rt) {
    int row = rt * 16 + lr;
    float s = 0.f, q = 0.f;
    #pragma unroll
    for (int u = 0; u < 8; ++u) { s += smP[u * 64 + row]; q += sqP[u * 64 + row]; }
    float me = s * invNC;
    float var = q * invNC - me * me;
    mean[rt] = me; rstd[rt] = rsqrtf(var + LNEPS);
  }
}

// ---------------- fused 3-layer MLP block ----------------
// 64 rows/block, 512 threads = 8 waves column-split (NTW = 2/4/2).
// __launch_bounds__(512) with NO min-waves clamp: peak live set ~170 regs
// (L2: acc 64 + af 16 + residb 16 + bw pipeline + addressing) — the unified
// VGPR+AGPR file allocates it without scratch spill at 2-3 waves/SIMD.
// R4-R8 history: forcing 128 regs (4 waves/EU) spilled 360-460MB to scratch;
// 16-wave split (R8) killed spill but halved LDS amortization. This keeps both.
template <int NKCIN, int INSTRIDE, int REGEL, bool KPOOL>
__global__ __launch_bounds__(512) void k_mlp(
    const float* __restrict__ pts, const int* __restrict__ idxp,
    const float* __restrict__ stdv, const float* __restrict__ alpha,
    const float* __restrict__ beta, const bf16_t* __restrict__ pooled1_in,
    const bf16_t* __restrict__ Wp0, const float* __restrict__ b0,
    const float* __restrict__ g0, const float* __restrict__ be0,
    const bf16_t* __restrict__ Wp1, const float* __restrict__ b1,
    const float* __restrict__ g1, const float* __restrict__ be1,
    const bf16_t* __restrict__ Wp2, const float* __restrict__ b2,
    const float* __restrict__ g2, const float* __restrict__ be2,
    bf16_t* __restrict__ pooled1_out, unsigned* __restrict__ pooled2)
{
  __shared__ bf16_t region[REGEL];
  __shared__ float smP[8 * 64];
  __shared__ float sqP[8 * 64];
  bf16_t* inS = region;                     // [64][INSTRIDE]; dead after L1 gemm
  bf16_t* yS = region + 64 * INSTRIDE;      // [64][264]
  bf16_t* hS = region;                      // [64][520], overlays after L2 reads done

  const int tid = threadIdx.x;
  const int l = tid & 63, w = tid >> 6;
  const int lr = l & 15, lg = l >> 4;
  const int p0 = blockIdx.x * (KPOOL ? 4 : 64);
  const int bb = p0 >> 12;

  // ---- stage input rows (64 rows; 8 col-chunks of 16) ----
  {
    const int r = tid >> 3, q = tid & 7;
    if (KPOOL) {
      const float inv = 1.0f / (stdv[bb] + STDEPS);
      const int p = p0 + (r >> 4), k = r & 15;
      if (q < 4) {
        const int ni = idxp[p * 16 + k];
        const float* sn = pts + ((size_t)(bb << 12) + ni) * 64 + q * 16;
        const float* sp = pts + (size_t)p * 64 + q * 16;
        #pragma unroll
        for (int i = 0; i < 4; ++i) {
          f32x4 a = *(const f32x4*)(sn + 4 * i);
          f32x4 c = *(const f32x4*)(sp + 4 * i);
          f32x4 av = *(const f32x4*)(alpha + q * 16 + 4 * i);
          f32x4 bv = *(const f32x4*)(beta + q * 16 + 4 * i);
          f32x4 v = (a - c) * (av * inv) + bv;
          *(bf16x4*)(inS + r * INSTRIDE + q * 16 + 4 * i) = cvt4(v);
        }
      } else {
        const float* sp = pts + (size_t)p * 64 + (q - 4) * 16;
        #pragma unroll
        for (int i = 0; i < 4; ++i) {
          f32x4 c = *(const f32x4*)(sp + 4 * i);
          *(bf16x4*)(inS + r * INSTRIDE + 64 + (q - 4) * 16 + 4 * i) = cvt4(c);
        }
      }
    } else {
      #pragma unroll
      for (int j = 0; j < 4; ++j) {
        *(bf16x8*)(inS + r * INSTRIDE + q * 32 + j * 8) =
            *(const bf16x8*)(pooled1_in + (size_t)(p0 + r) * 256 + q * 32 + j * 8);
      }
    }
  }
  __syncthreads();

  bf16x4 residb[2][4];                       // LN1 output, bf16 (matches LDS rounding)
  float mean[4], rstd[4];

  // ---- L1: IN -> 256, LN (no relu) ----
  {
    f32x4 acc[2][4];
    #pragma unroll
    for (int ct = 0; ct < 2; ++ct)
      #pragma unroll
      for (int rt = 0; rt < 4; ++rt) acc[ct][rt] = {0.f, 0.f, 0.f, 0.f};
    gemm_sw<NKCIN, 2>(inS, INSTRIDE, Wp0, w * 2, l, acc);
    float sm[4] = {0.f, 0.f, 0.f, 0.f}, sq[4] = {0.f, 0.f, 0.f, 0.f};
    add_bias_acc<2>(acc, b0, w * 2, lg, sm, sq);
    stats_store(sm, sq, w, l, smP, sqP);
    __syncthreads();
    mean_rstd(smP, sqP, lr, 1.f / 256.f, mean, rstd);
    #pragma unroll
    for (int ct = 0; ct < 2; ++ct) {
      const int t = w * 2 + ct;
      f32x4 g4 = *(const f32x4*)(g0 + t * 16 + 4 * lg);
      f32x4 be4 = *(const f32x4*)(be0 + t * 16 + 4 * lg);
      #pragma unroll
      for (int rt = 0; rt < 4; ++rt) {
        f32x4 v;
        #pragma unroll
        for (int rg = 0; rg < 4; ++rg)
          v[rg] = (acc[ct][rt][rg] - mean[rt]) * rstd[rt] * g4[rg] + be4[rg];
        bf16x4 vb = cvt4(v);
        residb[ct][rt] = vb;
        *(bf16x4*)(yS + (rt * 16 + lr) * 264 + t * 16 + 4 * lg) = vb;
      }
    }
  }
  __syncthreads();

  // ---- L2: 256 -> 512, LN + relu ----
  {
    f32x4 acc[4][4];
    #pragma unroll
    for (int ct = 0; ct < 4; ++ct)
      #pragma unroll
      for (int rt = 0; rt < 4; ++rt) acc[ct][rt] = {0.f, 0.f, 0.f, 0.f};
    gemm_sw<8, 4>(yS, 264, Wp1, w * 4, l, acc);
    float sm[4] = {0.f, 0.f, 0.f, 0.f}, sq[4] = {0.f, 0.f, 0.f, 0.f};
    add_bias_acc<4>(acc, b1, w * 4, lg, sm, sq);
    stats_store(sm, sq, w, l, smP, sqP);
    __syncthreads();   // stats ready; all yS/inS reads done -> hS may overlay
    mean_rstd(smP, sqP, lr, 1.f / 512.f, mean, rstd);
    #pragma unroll
    for (int ct = 0; ct < 4; ++ct) {
      const int t = w * 4 + ct;
      f32x4 g4 = *(const f32x4*)(g1 + t * 16 + 4 * lg);
      f32x4 be4 = *(const f32x4*)(be1 + t * 16 + 4 * lg);
      #pragma unroll
      for (int rt = 0; rt < 4; ++rt) {
        f32x4 v;
        #pragma unroll
        for (int rg = 0; rg < 4; ++rg)
          v[rg] = fmaxf(0.f, (acc[ct][rt][rg] - mean[rt]) * rstd[rt] * g4[rg] + be4[rg]);
        *(bf16x4*)(hS + (rt * 16 + lr) * 520 + t * 16 + 4 * lg) = cvt4(v);
      }
    }
  }
  __syncthreads();

  // ---- L3: 512 -> 256, resid + LN + relu, pool ----
  {
    f32x4 acc[2][4];
    #pragma unroll
    for (int ct = 0; ct < 2; ++ct)
      #pragma unroll
      for (int rt = 0; rt < 4; ++rt) acc[ct][rt] = {0.f, 0.f, 0.f, 0.f};
    gemm_sw<16, 2>(hS, 520, Wp2, w * 2, l, acc);
    float sm[4] = {0.f, 0.f, 0.f, 0.f}, sq[4] = {0.f, 0.f, 0.f, 0.f};
    add_bias_acc<2>(acc, b2, w * 2, lg, sm, sq);
    stats_store(sm, sq, w, l, smP, sqP);
    __syncthreads();
    mean_rstd(smP, sqP, lr, 1.f / 256.f, mean, rstd);
    #pragma unroll
    for (int ct = 0; ct < 2; ++ct) {
      const int t = w * 2 + ct;
      f32x4 g4 = *(const f32x4*)(g2 + t * 16 + 4 * lg);
      f32x4 be4 = *(const f32x4*)(be2 + t * 16 + 4 * lg);
      f32x4 mv = {0.f, 0.f, 0.f, 0.f};
      #pragma unroll
      for (int rt = 0; rt < 4; ++rt) {
        f32x4 v;
        #pragma unroll
        for (int rg = 0; rg < 4; ++rg)
          v[rg] = fmaxf(0.f, (float)residb[ct][rt][rg] +
                             (acc[ct][rt][rg] - mean[rt]) * rstd[rt] * g4[rg] + be4[rg]);
        if (KPOOL) {
          v = shflmax(v, 1); v = shflmax(v, 2); v = shflmax(v, 4); v = shflmax(v, 8);
          if (lr == 0)
            *(bf16x4*)(pooled1_out + (size_t)(p0 + rt) * 256 + t * 16 + 4 * lg) = cvt4(v);
        } else {
          #pragma unroll
          for (int rg = 0; rg < 4; ++rg) mv[rg] = fmaxf(mv[rg], v[rg]);
        }
      }
      if (!KPOOL) {
        mv = shflmax(mv, 1); mv = shflmax(mv, 2); mv = shflmax(mv, 4); mv = shflmax(mv, 8);
        if (lr == 0) {
          #pragma unroll
          for (int rg = 0; rg < 4; ++rg)
            atomicMax(&pooled2[bb * 256 + t * 16 + 4 * lg + rg], __float_as_uint(mv[rg]));
        }
      }
    }
  }
}

// ---------------- final head ----------------
__global__ void k_final(const unsigned* __restrict__ pooled2,
                        const float* __restrict__ W, const float* __restrict__ bb,
                        const float* __restrict__ g, const float* __restrict__ be,
                        float* __restrict__ out)
{
  int w = threadIdx.x >> 6;
  int l = threadIdx.x & 63;
  float acc = bb[l];
  for (int k = 0; k < 256; ++k)
    acc = fmaf(__uint_as_float(pooled2[w * 256 + k]), W[k * 64 + l], acc);
  float sm = acc, sq = acc * acc;
  #pragma unroll
  for (int m = 1; m < 64; m <<= 1) {
    sm += __shfl_xor(sm, m, 64);
    sq += __shfl_xor(sq, m, 64);
  }
  float mean = sm * (1.f / 64.f);
  float var = sq * (1.f / 64.f) - mean * mean;
  out[w * 64 + l] = (acc - mean) * rsqrtf(var + LNEPS) * g[l] + be[l];
}

// ---------------- launch ----------------
extern "C" void kernel_launch(void* const* d_in, const int* in_sizes, int n_in,
                              void* d_out, int out_size, void* d_ws, size_t ws_size,
                              hipStream_t stream)
{
  if (ws_size < WS_NEED) return;
  const float* xyz = (const float*)d_in[0];
  const float* x = (const float*)d_in[1];
  const float* W_emb = (const float*)d_in[2];
  const float* b_emb = (const float*)d_in[3];
  const float* g_emb = (const float*)d_in[4];
  const float* be_emb = (const float*)d_in[5];
  const float* alpha = (const float*)d_in[6];
  const float* beta = (const float*)d_in[7];
  const float* W_pre = (const float*)d_in[8];
  const float* b_pre = (const float*)d_in[9];
  const float* g_pre = (const float*)d_in[10];
  const float* be_pre = (const float*)d_in[11];
  const float* W1a = (const float*)d_in[12];
  const float* b1a = (const float*)d_in[13];
  const float* g1a = (const float*)d_in[14];
  const float* be1a = (const float*)d_in[15];
  const float* W2a = (const float*)d_in[16];
  const float* b2a = (const float*)d_in[17];
  const float* g2a = (const float*)d_in[18];
  const float* be2a = (const float*)d_in[19];
  const float* W_pos = (const float*)d_in[20];
  const float* b_pos = (const float*)d_in[21];
  const float* g_pos = (const float*)d_in[22];
  const float* be_pos = (const float*)d_in[23];
  const float* W1b = (const float*)d_in[24];
  const float* b1b = (const float*)d_in[25];
  const float* g1b = (const float*)d_in[26];
  const float* be1b = (const float*)d_in[27];
  const float* W2b = (const float*)d_in[28];
  const float* b2b = (const float*)d_in[29];
  const float* g2b = (const float*)d_in[30];
  const float* be2b = (const float*)d_in[31];
  const float* W_fin = (const float*)d_in[32];
  const float* b_fin = (const float*)d_in[33];
  const float* g_fin = (const float*)d_in[34];
  const float* be_fin = (const float*)d_in[35];

  char* ws = (char*)d_ws;
  float* pts = (float*)(ws + PTS_OFF);
  int* idx = (int*)(ws + IDX_OFF);
  double* red = (double*)(ws + RED_OFF);
  float* stdv = (float*)(ws + STD_OFF);
  bf16_t* WpPre = (bf16_t*)(ws + WP_OFF);
  bf16_t* Wp1a = WpPre + 32768;
  bf16_t* Wp2a = Wp1a + 131072;
  bf16_t* WpPos = Wp2a + 131072;
  bf16_t* Wp1b = WpPos + 65536;
  bf16_t* Wp2b = Wp1b + 131072;
  bf16_t* pooled1 = (bf16_t*)(ws + POOL1_OFF);
  float4* cand4 = (float4*)(ws + POOL1_OFF);   // overlays pooled1; disjoint lifetime
  unsigned* pooled2 = (unsigned*)(ws + POOL2_OFF);

  hipMemsetAsync(ws + RED_OFF, 0, 256, stream);
  hipMemsetAsync(ws + POOL2_OFF, 0, 8192, stream);

  k_pack<<<32768 / 256, 256, 0, stream>>>(W_pre, WpPre, 256, 2, 32768);
  k_pack<<<131072 / 256, 256, 0, stream>>>(W1a, Wp1a, 512, 3, 131072);
  k_pack<<<131072 / 256, 256, 0, stream>>>(W2a, Wp2a, 256, 4, 131072);
  k_pack<<<65536 / 256, 256, 0, stream>>>(W_pos, WpPos, 256, 3, 65536);
  k_pack<<<131072 / 256, 256, 0, stream>>>(W1b, Wp1b, 512, 3, 131072);
  k_pack<<<131072 / 256, 256, 0, stream>>>(W2b, Wp2b, 256, 4, 131072);

  k_embed<<<32768 / 256, 256, 0, stream>>>(xyz, x, W_emb, b_emb, g_emb, be_emb, pts, cand4);
  k_knn<<<512, 256, 0, stream>>>(cand4, idx);
  k_stdred<<<512, 256, 0, stream>>>(pts, idx, red);
  k_stdfin<<<1, 64, 0, stream>>>(red, stdv);

  k_mlp<4, 136, 33280, true><<<8192, 512, 0, stream>>>(
      pts, idx, stdv, alpha, beta, nullptr,
      WpPre, b_pre, g_pre, be_pre,
      Wp1a, b1a, g1a, be1a,
      Wp2a, b2a, g2a, be2a,
      pooled1, nullptr);
  k_mlp<8, 264, 33792, false><<<512, 512, 0, stream>>>(
      nullptr, nullptr, nullptr, nullptr, nullptr, pooled1,
      WpPos, b_pos, g_pos, be_pos,
      Wp1b, b1b, g1b, be1b,
      Wp2b, b2b, g2b, be2b,
      nullptr, pooled2);
  k_final<<<1, 512, 0, stream>>>(pooled2, W_fin, b_fin, g_fin, be_fin, (float*)d_out);
}

// Round 11
// 939.705 us; speedup vs baseline: 1.2222x; 1.0087x over previous
//
#include <hip/hip_runtime.h>
#include <hip/hip_bf16.h>

typedef __bf16 bf16_t;
typedef __bf16 bf16x8 __attribute__((ext_vector_type(8)));
typedef __bf16 bf16x4 __attribute__((ext_vector_type(4)));
typedef float f32x4 __attribute__((ext_vector_type(4)));
typedef unsigned long long u64;

#define LNEPS 1e-5f
#define STDEPS 1e-5f

// ---------------- workspace layout (bytes) ----------------
#define PTS_OFF   0UL           // f32 [8*4096*64]          = 8388608
#define IDX_OFF   8519680UL     // i32 [8*4096*16]          = 2097152
#define RED_OFF   10616832UL    // f64 sums[8],sumsq[8] + f32 std[8]
#define STD_OFF   (RED_OFF + 128UL)
#define WP_OFF    10617088UL    // packed bf16 weights      = 1245184
#define POOL1_OFF 11862272UL    // bf16 [32768*256] ; cand4 f32x4[32768] overlays (disjoint lifetime)
#define POOL2_OFF 28639488UL    // u32/f32 [8*256]          = 8192
#define WS_NEED   28647680UL

// ---------------- weight pack: W[Ni][No] f32 -> MFMA frag-contiguous bf16 ----------------
__global__ void k_pack(const float* __restrict__ W, bf16_t* __restrict__ Wp,
                       int No, int sh, int n)
{
  int i = blockIdx.x * 256 + threadIdx.x;
  if (i >= n) return;
  int j = i & 7;
  int l = (i >> 3) & 63;
  int rest = i >> 9;
  int kc = rest & ((1 << sh) - 1);
  int t = rest >> sh;
  int k = kc * 32 + (l >> 4) * 8 + j;
  int col = t * 16 + (l & 15);
  Wp[i] = (bf16_t)W[k * No + col];
}

// ---------------- embedding: pts = relu(LN(x@W_emb+b_emb)); cand4 = [xyz, |xyz|^2] ----------------
__global__ void k_embed(const float* __restrict__ xyz, const float* __restrict__ x,
                        const float* __restrict__ W, const float* __restrict__ bb,
                        const float* __restrict__ g, const float* __restrict__ be,
                        float* __restrict__ pts, float4* __restrict__ cand4)
{
  int p = blockIdx.x * 256 + threadIdx.x;
  float x0 = x[p * 3 + 0], x1 = x[p * 3 + 1], x2 = x[p * 3 + 2];
  float e[64];
  float s = 0.f;
  #pragma unroll
  for (int j = 0; j < 64; ++j) {
    float v = bb[j];
    v = fmaf(x0, W[j], v);
    v = fmaf(x1, W[64 + j], v);
    v = fmaf(x2, W[128 + j], v);
    e[j] = v; s += v;
  }
  float mean = s * (1.f / 64.f);
  float vs = 0.f;
  #pragma unroll
  for (int j = 0; j < 64; ++j) { float d = e[j] - mean; vs = fmaf(d, d, vs); }
  float rstd = rsqrtf(vs * (1.f / 64.f) + LNEPS);
  #pragma unroll
  for (int j = 0; j < 64; ++j)
    pts[p * 64 + j] = fmaxf(0.f, (e[j] - mean) * rstd * g[j] + be[j]);
  float z0 = xyz[p * 3 + 0], z1 = xyz[p * 3 + 1], z2 = xyz[p * 3 + 2];
  cand4[p] = make_float4(z0, z1, z2, z0 * z0 + z1 * z1 + z2 * z2);
}

// ---------------- KNN helpers ----------------
__device__ __forceinline__ void insert16(u64* a, u64 key)
{
  #pragma unroll
  for (int j = 15; j >= 1; --j) {
    u64 lo = (key < a[j - 1]) ? a[j - 1] : key;
    a[j] = (key < a[j]) ? lo : a[j];
  }
  a[0] = (key < a[0]) ? key : a[0];
}

__device__ __forceinline__ void merge16(u64* a, const u64* b)
{
  u64 m[16];
  #pragma unroll
  for (int i = 0; i < 16; ++i) m[i] = (a[i] < b[15 - i]) ? a[i] : b[15 - i];
  #pragma unroll
  for (int d = 8; d >= 1; d >>= 1) {
    #pragma unroll
    for (int i = 0; i < 16; ++i) {
      if ((i & d) == 0) {
        u64 xv = m[i], yv = m[i + d];
        bool c = yv < xv;
        m[i] = c ? yv : xv;
        m[i + d] = c ? xv : yv;
      }
    }
  }
  #pragma unroll
  for (int i = 0; i < 16; ++i) a[i] = m[i];
}

// 512 thr = 8 waves; lane = query (64 queries/block), wave scans its 512-candidate chunk.
__global__ __launch_bounds__(512) void k_knn(const float4* __restrict__ cand4,
                                             int* __restrict__ idx)
{
  __shared__ u64 ldsB[512 * 17];
  const int tid = threadIdx.x;
  const int l = tid & 63;
  const int w = tid >> 6;
  const int wu = __builtin_amdgcn_readfirstlane(w);
  const int b = blockIdx.x >> 6;
  const int g = blockIdx.x & 63;
  const int p = (b << 12) + (g << 6) + l;
  const float4 q = cand4[p];
  const float4* __restrict__ cbase = cand4 + (b << 12) + (wu << 9);
  const int mbase = wu << 9;
  u64 arr[16];
  const u64 KINF = ((u64)0x7F800000u << 32) | 0xFFFFFFFFu;
  #pragma unroll
  for (int j = 0; j < 16; ++j) arr[j] = KINF;
  float tf = 3.4e38f;
  int cnt = 0;
  u64* myb = &ldsB[tid * 17];

  for (int m0 = 0; m0 < 512; m0 += 8) {
    if (__any(cnt > 8)) {
      for (int j2 = 0; j2 < cnt; ++j2) insert16(arr, myb[j2]);
      cnt = 0;
      tf = __uint_as_float((unsigned)(arr[15] >> 32));
    }
    #pragma unroll
    for (int u = 0; u < 8; ++u) {
      float4 c = cbase[m0 + u];
      float dot = q.x * c.x;
      dot = fmaf(q.y, c.y, dot);
      dot = fmaf(q.z, c.z, dot);
      float d = fmaxf(fmaf(-2.f, dot, q.w + c.w), 0.f);
      if (d < tf) {
        myb[cnt] = ((u64)__float_as_uint(d) << 32) | (unsigned)(mbase + m0 + u);
        ++cnt;
      }
    }
  }
  for (int j2 = 0; j2 < cnt; ++j2) insert16(arr, myb[j2]);

  // publish sorted list, then 3-level tree-merge across the 8 waves
  #pragma unroll
  for (int j = 0; j < 16; ++j) myb[j] = arr[j];
  __syncthreads();
  if ((w & 1) == 0) {
    u64 brr[16];
    #pragma unroll
    for (int j = 0; j < 16; ++j) brr[j] = ldsB[((w + 1) * 64 + l) * 17 + j];
    merge16(arr, brr);
    #pragma unroll
    for (int j = 0; j < 16; ++j) myb[j] = arr[j];
  }
  __syncthreads();
  if ((w & 3) == 0) {
    u64 brr[16];
    #pragma unroll
    for (int j = 0; j < 16; ++j) brr[j] = ldsB[((w + 2) * 64 + l) * 17 + j];
    merge16(arr, brr);
    #pragma unroll
    for (int j = 0; j < 16; ++j) myb[j] = arr[j];
  }
  __syncthreads();
  if (w == 0) {
    u64 brr[16];
    #pragma unroll
    for (int j = 0; j < 16; ++j) brr[j] = ldsB[(4 * 64 + l) * 17 + j];
    merge16(arr, brr);
    #pragma unroll
    for (int j = 0; j < 16; ++j) idx[p * 16 + j] = (int)(unsigned)(arr[j] & 0xFFFFFFFFu);
  }
}

// ---------------- std reduction over diff = pts[idx] - pts (per batch) ----------------
__global__ void k_stdred(const float* __restrict__ pts, const int* __restrict__ idx,
                         double* __restrict__ red)
{
  int b = blockIdx.x >> 6, chunk = blockIdx.x & 63;
  int tid = threadIdx.x;
  int h = tid & 63;
  int r0 = chunk * 1024 + (tid >> 6);
  float s = 0.f, s2 = 0.f;
  for (int i = 0; i < 256; ++i) {
    int row = r0 + 4 * i;
    int n = row >> 4, k = row & 15;
    int ni = idx[((b << 12) + n) * 16 + k];
    float v = pts[((b << 12) + ni) * 64 + h] - pts[((b << 12) + n) * 64 + h];
    s += v; s2 = fmaf(v, v, s2);
  }
  double ds = (double)s, ds2 = (double)s2;
  #pragma unroll
  for (int m = 1; m < 64; m <<= 1) {
    ds += __shfl_xor(ds, m, 64);
    ds2 += __shfl_xor(ds2, m, 64);
  }
  __shared__ double sred[8];
  int w = tid >> 6;
  if ((tid & 63) == 0) { sred[w] = ds; sred[4 + w] = ds2; }
  __syncthreads();
  if (tid == 0) {
    atomicAdd(&red[b], sred[0] + sred[1] + sred[2] + sred[3]);
    atomicAdd(&red[8 + b], sred[4] + sred[5] + sred[6] + sred[7]);
  }
}

__global__ void k_stdfin(const double* __restrict__ red, float* __restrict__ stdv)
{
  int t = threadIdx.x;
  if (t < 8) {
    double M = 4194304.0;
    double s = red[t], s2 = red[8 + t];
    double var = (s2 - s * s / M) / (M - 1.0);
    stdv[t] = (float)sqrt(var);
  }
}

// ---------------- MLP helpers (swapped-operand MFMA: D[outcol][datarow]) ----------------
__device__ __forceinline__ bf16x4 cvt4(f32x4 v)
{
  bf16x4 o;
  o[0] = (bf16_t)v[0]; o[1] = (bf16_t)v[1]; o[2] = (bf16_t)v[2]; o[3] = (bf16_t)v[3];
  return o;
}

__device__ __forceinline__ f32x4 vmax0(f32x4 v)
{
  f32x4 r;
  #pragma unroll
  for (int c = 0; c < 4; ++c) r[c] = fmaxf(v[c], 0.f);
  return r;
}

__device__ __forceinline__ f32x4 shflmax(f32x4 v, int m)
{
  f32x4 r;
  #pragma unroll
  for (int c = 0; c < 4; ++c) r[c] = fmaxf(v[c], __shfl_xor(v[c], m, 64));
  return r;
}

// GEMM over col-tiles t0..t0+NTW-1, all 4 row-tiles (64 rows).
template <int NKC, int NTW>
__device__ __forceinline__ void gemm_sw(const bf16_t* __restrict__ inS, const int instride,
                                        const bf16_t* __restrict__ Wp,
                                        const int t0, const int l, f32x4 (*acc)[4])
{
  const int lr = l & 15, lg = l >> 4;
  const bf16x8* __restrict__ Wf = (const bf16x8*)Wp;
  #pragma unroll
  for (int kc = 0; kc < NKC; ++kc) {
    bf16x8 af[4];
    #pragma unroll
    for (int rt = 0; rt < 4; ++rt)
      af[rt] = *(const bf16x8*)(inS + (rt * 16 + lr) * instride + kc * 32 + lg * 8);
    #pragma unroll
    for (int ct = 0; ct < NTW; ++ct) {
      bf16x8 bw = Wf[((t0 + ct) * NKC + kc) * 64 + l];
      #pragma unroll
      for (int rt = 0; rt < 4; ++rt)
        acc[ct][rt] = __builtin_amdgcn_mfma_f32_16x16x32_bf16(bw, af[rt], acc[ct][rt], 0, 0, 0);
    }
  }
}

// add bias in-place; accumulate per-row-tile partial sums as f32x4 vectors (pk-math)
template <int NTW>
__device__ __forceinline__ void add_bias_acc(f32x4 (*acc)[4], const float* __restrict__ bias,
                                             const int t0, const int lg,
                                             f32x4* smv, f32x4* sqv)
{
  #pragma unroll
  for (int ct = 0; ct < NTW; ++ct) {
    f32x4 b4 = *(const f32x4*)(bias + (t0 + ct) * 16 + 4 * lg);
    #pragma unroll
    for (int rt = 0; rt < 4; ++rt) {
      f32x4 v = acc[ct][rt] + b4;
      acc[ct][rt] = v;
      smv[rt] += v;
      sqv[rt] = v * v + sqv[rt];
    }
  }
}

// horizontal + lg-axis shuffle reduce + per-wave partial store (8 waves)
__device__ __forceinline__ void stats_store(const f32x4* smv, const f32x4* sqv,
                                            const int w, const int l,
                                            float* __restrict__ smP, float* __restrict__ sqP)
{
  const int lr = l & 15, lg = l >> 4;
  float sm[4], sq[4];
  #pragma unroll
  for (int rt = 0; rt < 4; ++rt) {
    sm[rt] = (smv[rt][0] + smv[rt][1]) + (smv[rt][2] + smv[rt][3]);
    sq[rt] = (sqv[rt][0] + sqv[rt][1]) + (sqv[rt][2] + sqv[rt][3]);
    sm[rt] += __shfl_xor(sm[rt], 16, 64); sq[rt] += __shfl_xor(sq[rt], 16, 64);
    sm[rt] += __shfl_xor(sm[rt], 32, 64); sq[rt] += __shfl_xor(sq[rt], 32, 64);
  }
  if (lg == 0) {
    #pragma unroll
    for (int rt = 0; rt < 4; ++rt) {
      smP[w * 64 + rt * 16 + lr] = sm[rt];
      sqP[w * 64 + rt * 16 + lr] = sq[rt];
    }
  }
}

__device__ __forceinline__ void mean_rstd(const float* __restrict__ smP,
                                          const float* __restrict__ sqP,
                                          const int lr, const float invNC,
                                          float* mean, float* rstd)
{
  #pragma unroll
  for (int rt = 0; rt < 4; ++rt) {
    int row = rt * 16 + lr;
    float s = 0.f, q = 0.f;
    #pragma unroll
    for (int u = 0; u < 8; ++u) { s += smP[u * 64 + row]; q += sqP[u * 64 + row]; }
    float me = s * invNC;
    float var = q * invNC - me * me;
    mean[rt] = me; rstd[rt] = rsqrtf(var + LNEPS);
  }
}

// ---------------- fused 3-layer MLP block ----------------
// 64 rows/block, 512 threads = 8 waves column-split (NTW = 2/4/2).
// __launch_bounds__(512), no min-waves clamp (R9: no spill, WRITE=16MB ideal).
// Epilogue math is all f32x4 vector expressions -> v_pk_*_f32 (2x f32/instr),
// LN folded to a single vector FMA via per-(ct,rt) scale/shift (R9: VALU was
// the largest pipe at 266us/CU, phases serialize so VALU cut = wall cut).
template <int NKCIN, int INSTRIDE, int REGEL, bool KPOOL>
__global__ __launch_bounds__(512) void k_mlp(
    const float* __restrict__ pts, const int* __restrict__ idxp,
    const float* __restrict__ stdv, const float* __restrict__ alpha,
    const float* __restrict__ beta, const bf16_t* __restrict__ pooled1_in,
    const bf16_t* __restrict__ Wp0, const float* __restrict__ b0,
    const float* __restrict__ g0, const float* __restrict__ be0,
    const bf16_t* __restrict__ Wp1, const float* __restrict__ b1,
    const float* __restrict__ g1, const float* __restrict__ be1,
    const bf16_t* __restrict__ Wp2, const float* __restrict__ b2,
    const float* __restrict__ g2, const float* __restrict__ be2,
    bf16_t* __restrict__ pooled1_out, unsigned* __restrict__ pooled2)
{
  __shared__ bf16_t region[REGEL];
  __shared__ float smP[8 * 64];
  __shared__ float sqP[8 * 64];
  bf16_t* inS = region;                     // [64][INSTRIDE]; dead after L1 gemm
  bf16_t* yS = region + 64 * INSTRIDE;      // [64][264]
  bf16_t* hS = region;                      // [64][520], overlays after L2 reads done

  const int tid = threadIdx.x;
  const int l = tid & 63, w = tid >> 6;
  const int lr = l & 15, lg = l >> 4;
  const int p0 = blockIdx.x * (KPOOL ? 4 : 64);
  const int bb = p0 >> 12;

  // ---- stage input rows (64 rows; 8 col-chunks of 16) ----
  {
    const int r = tid >> 3, q = tid & 7;
    if (KPOOL) {
      const float inv = 1.0f / (stdv[bb] + STDEPS);
      const int p = p0 + (r >> 4), k = r & 15;
      if (q < 4) {
        const int ni = idxp[p * 16 + k];
        const float* sn = pts + ((size_t)(bb << 12) + ni) * 64 + q * 16;
        const float* sp = pts + (size_t)p * 64 + q * 16;
        #pragma unroll
        for (int i = 0; i < 4; ++i) {
          f32x4 a = *(const f32x4*)(sn + 4 * i);
          f32x4 c = *(const f32x4*)(sp + 4 * i);
          f32x4 av = *(const f32x4*)(alpha + q * 16 + 4 * i);
          f32x4 bv = *(const f32x4*)(beta + q * 16 + 4 * i);
          f32x4 v = (a - c) * (av * inv) + bv;
          *(bf16x4*)(inS + r * INSTRIDE + q * 16 + 4 * i) = cvt4(v);
        }
      } else {
        const float* sp = pts + (size_t)p * 64 + (q - 4) * 16;
        #pragma unroll
        for (int i = 0; i < 4; ++i) {
          f32x4 c = *(const f32x4*)(sp + 4 * i);
          *(bf16x4*)(inS + r * INSTRIDE + 64 + (q - 4) * 16 + 4 * i) = cvt4(c);
        }
      }
    } else {
      #pragma unroll
      for (int j = 0; j < 4; ++j) {
        *(bf16x8*)(inS + r * INSTRIDE + q * 32 + j * 8) =
            *(const bf16x8*)(pooled1_in + (size_t)(p0 + r) * 256 + q * 32 + j * 8);
      }
    }
  }
  __syncthreads();

  bf16x4 residb[2][4];                       // LN1 output, bf16 (matches LDS rounding)
  float mean[4], rstd[4];

  // ---- L1: IN -> 256, LN (no relu) ----
  {
    f32x4 acc[2][4];
    f32x4 smv[4], sqv[4];
    #pragma unroll
    for (int rt = 0; rt < 4; ++rt) { smv[rt] = {0,0,0,0}; sqv[rt] = {0,0,0,0}; }
    #pragma unroll
    for (int ct = 0; ct < 2; ++ct)
      #pragma unroll
      for (int rt = 0; rt < 4; ++rt) acc[ct][rt] = {0.f, 0.f, 0.f, 0.f};
    gemm_sw<NKCIN, 2>(inS, INSTRIDE, Wp0, w * 2, l, acc);
    add_bias_acc<2>(acc, b0, w * 2, lg, smv, sqv);
    stats_store(smv, sqv, w, l, smP, sqP);
    __syncthreads();
    mean_rstd(smP, sqP, lr, 1.f / 256.f, mean, rstd);
    #pragma unroll
    for (int ct = 0; ct < 2; ++ct) {
      const int t = w * 2 + ct;
      f32x4 g4 = *(const f32x4*)(g0 + t * 16 + 4 * lg);
      f32x4 be4 = *(const f32x4*)(be0 + t * 16 + 4 * lg);
      #pragma unroll
      for (int rt = 0; rt < 4; ++rt) {
        f32x4 scale = g4 * rstd[rt];
        f32x4 shift = be4 - mean[rt] * scale;
        f32x4 v = acc[ct][rt] * scale + shift;
        bf16x4 vb = cvt4(v);
        residb[ct][rt] = vb;
        *(bf16x4*)(yS + (rt * 16 + lr) * 264 + t * 16 + 4 * lg) = vb;
      }
    }
  }
  __syncthreads();

  // ---- L2: 256 -> 512, LN + relu ----
  {
    f32x4 acc[4][4];
    f32x4 smv[4], sqv[4];
    #pragma unroll
    for (int rt = 0; rt < 4; ++rt) { smv[rt] = {0,0,0,0}; sqv[rt] = {0,0,0,0}; }
    #pragma unroll
    for (int ct = 0; ct < 4; ++ct)
      #pragma unroll
      for (int rt = 0; rt < 4; ++rt) acc[ct][rt] = {0.f, 0.f, 0.f, 0.f};
    gemm_sw<8, 4>(yS, 264, Wp1, w * 4, l, acc);
    add_bias_acc<4>(acc, b1, w * 4, lg, smv, sqv);
    stats_store(smv, sqv, w, l, smP, sqP);
    __syncthreads();   // stats ready; all yS/inS reads done -> hS may overlay
    mean_rstd(smP, sqP, lr, 1.f / 512.f, mean, rstd);
    #pragma unroll
    for (int ct = 0; ct < 4; ++ct) {
      const int t = w * 4 + ct;
      f32x4 g4 = *(const f32x4*)(g1 + t * 16 + 4 * lg);
      f32x4 be4 = *(const f32x4*)(be1 + t * 16 + 4 * lg);
      #pragma unroll
      for (int rt = 0; rt < 4; ++rt) {
        f32x4 scale = g4 * rstd[rt];
        f32x4 shift = be4 - mean[rt] * scale;
        f32x4 v = vmax0(acc[ct][rt] * scale + shift);
        *(bf16x4*)(hS + (rt * 16 + lr) * 520 + t * 16 + 4 * lg) = cvt4(v);
      }
    }
  }
  __syncthreads();

  // ---- L3: 512 -> 256, resid + LN + relu, pool ----
  {
    f32x4 acc[2][4];
    f32x4 smv[4], sqv[4];
    #pragma unroll
    for (int rt = 0; rt < 4; ++rt) { smv[rt] = {0,0,0,0}; sqv[rt] = {0,0,0,0}; }
    #pragma unroll
    for (int ct = 0; ct < 2; ++ct)
      #pragma unroll
      for (int rt = 0; rt < 4; ++rt) acc[ct][rt] = {0.f, 0.f, 0.f, 0.f};
    gemm_sw<16, 2>(hS, 520, Wp2, w * 2, l, acc);
    add_bias_acc<2>(acc, b2, w * 2, lg, smv, sqv);
    stats_store(smv, sqv, w, l, smP, sqP);
    __syncthreads();
    mean_rstd(smP, sqP, lr, 1.f / 256.f, mean, rstd);
    #pragma unroll
    for (int ct = 0; ct < 2; ++ct) {
      const int t = w * 2 + ct;
      f32x4 g4 = *(const f32x4*)(g2 + t * 16 + 4 * lg);
      f32x4 be4 = *(const f32x4*)(be2 + t * 16 + 4 * lg);
      f32x4 mv = {0.f, 0.f, 0.f, 0.f};
      #pragma unroll
      for (int rt = 0; rt < 4; ++rt) {
        f32x4 scale = g4 * rstd[rt];
        f32x4 shift = be4 - mean[rt] * scale;
        f32x4 r4;
        r4[0] = (float)residb[ct][rt][0]; r4[1] = (float)residb[ct][rt][1];
        r4[2] = (float)residb[ct][rt][2]; r4[3] = (float)residb[ct][rt][3];
        f32x4 v = vmax0(r4 + acc[ct][rt] * scale + shift);
        if (KPOOL) {
          v = shflmax(v, 1); v = shflmax(v, 2); v = shflmax(v, 4); v = shflmax(v, 8);
          if (lr == 0)
            *(bf16x4*)(pooled1_out + (size_t)(p0 + rt) * 256 + t * 16 + 4 * lg) = cvt4(v);
        } else {
          #pragma unroll
          for (int rg = 0; rg < 4; ++rg) mv[rg] = fmaxf(mv[rg], v[rg]);
        }
      }
      if (!KPOOL) {
        mv = shflmax(mv, 1); mv = shflmax(mv, 2); mv = shflmax(mv, 4); mv = shflmax(mv, 8);
        if (lr == 0) {
          #pragma unroll
          for (int rg = 0; rg < 4; ++rg)
            atomicMax(&pooled2[bb * 256 + t * 16 + 4 * lg + rg], __float_as_uint(mv[rg]));
        }
      }
    }
  }
}

// ---------------- final head ----------------
__global__ void k_final(const unsigned* __restrict__ pooled2,
                        const float* __restrict__ W, const float* __restrict__ bb,
                        const float* __restrict__ g, const float* __restrict__ be,
                        float* __restrict__ out)
{
  int w = threadIdx.x >> 6;
  int l = threadIdx.x & 63;
  float acc = bb[l];
  for (int k = 0; k < 256; ++k)
    acc = fmaf(__uint_as_float(pooled2[w * 256 + k]), W[k * 64 + l], acc);
  float sm = acc, sq = acc * acc;
  #pragma unroll
  for (int m = 1; m < 64; m <<= 1) {
    sm += __shfl_xor(sm, m, 64);
    sq += __shfl_xor(sq, m, 64);
  }
  float mean = sm * (1.f / 64.f);
  float var = sq * (1.f / 64.f) - mean * mean;
  out[w * 64 + l] = (acc - mean) * rsqrtf(var + LNEPS) * g[l] + be[l];
}

// ---------------- launch ----------------
extern "C" void kernel_launch(void* const* d_in, const int* in_sizes, int n_in,
                              void* d_out, int out_size, void* d_ws, size_t ws_size,
                              hipStream_t stream)
{
  if (ws_size < WS_NEED) return;
  const float* xyz = (const float*)d_in[0];
  const float* x = (const float*)d_in[1];
  const float* W_emb = (const float*)d_in[2];
  const float* b_emb = (const float*)d_in[3];
  const float* g_emb = (const float*)d_in[4];
  const float* be_emb = (const float*)d_in[5];
  const float* alpha = (const float*)d_in[6];
  const float* beta = (const float*)d_in[7];
  const float* W_pre = (const float*)d_in[8];
  const float* b_pre = (const float*)d_in[9];
  const float* g_pre = (const float*)d_in[10];
  const float* be_pre = (const float*)d_in[11];
  const float* W1a = (const float*)d_in[12];
  const float* b1a = (const float*)d_in[13];
  const float* g1a = (const float*)d_in[14];
  const float* be1a = (const float*)d_in[15];
  const float* W2a = (const float*)d_in[16];
  const float* b2a = (const float*)d_in[17];
  const float* g2a = (const float*)d_in[18];
  const float* be2a = (const float*)d_in[19];
  const float* W_pos = (const float*)d_in[20];
  const float* b_pos = (const float*)d_in[21];
  const float* g_pos = (const float*)d_in[22];
  const float* be_pos = (const float*)d_in[23];
  const float* W1b = (const float*)d_in[24];
  const float* b1b = (const float*)d_in[25];
  const float* g1b = (const float*)d_in[26];
  const float* be1b = (const float*)d_in[27];
  const float* W2b = (const float*)d_in[28];
  const float* b2b = (const float*)d_in[29];
  const float* g2b = (const float*)d_in[30];
  const float* be2b = (const float*)d_in[31];
  const float* W_fin = (const float*)d_in[32];
  const float* b_fin = (const float*)d_in[33];
  const float* g_fin = (const float*)d_in[34];
  const float* be_fin = (const float*)d_in[35];

  char* ws = (char*)d_ws;
  float* pts = (float*)(ws + PTS_OFF);
  int* idx = (int*)(ws + IDX_OFF);
  double* red = (double*)(ws + RED_OFF);
  float* stdv = (float*)(ws + STD_OFF);
  bf16_t* WpPre = (bf16_t*)(ws + WP_OFF);
  bf16_t* Wp1a = WpPre + 32768;
  bf16_t* Wp2a = Wp1a + 131072;
  bf16_t* WpPos = Wp2a + 131072;
  bf16_t* Wp1b = WpPos + 65536;
  bf16_t* Wp2b = Wp1b + 131072;
  bf16_t* pooled1 = (bf16_t*)(ws + POOL1_OFF);
  float4* cand4 = (float4*)(ws + POOL1_OFF);   // overlays pooled1; disjoint lifetime
  unsigned* pooled2 = (unsigned*)(ws + POOL2_OFF);

  hipMemsetAsync(ws + RED_OFF, 0, 256, stream);
  hipMemsetAsync(ws + POOL2_OFF, 0, 8192, stream);

  k_pack<<<32768 / 256, 256, 0, stream>>>(W_pre, WpPre, 256, 2, 32768);
  k_pack<<<131072 / 256, 256, 0, stream>>>(W1a, Wp1a, 512, 3, 131072);
  k_pack<<<131072 / 256, 256, 0, stream>>>(W2a, Wp2a, 256, 4, 131072);
  k_pack<<<65536 / 256, 256, 0, stream>>>(W_pos, WpPos, 256, 3, 65536);
  k_pack<<<131072 / 256, 256, 0, stream>>>(W1b, Wp1b, 512, 3, 131072);
  k_pack<<<131072 / 256, 256, 0, stream>>>(W2b, Wp2b, 256, 4, 131072);

  k_embed<<<32768 / 256, 256, 0, stream>>>(xyz, x, W_emb, b_emb, g_emb, be_emb, pts, cand4);
  k_knn<<<512, 512, 0, stream>>>(cand4, idx);
  k_stdred<<<512, 256, 0, stream>>>(pts, idx, red);
  k_stdfin<<<1, 64, 0, stream>>>(red, stdv);

  k_mlp<4, 136, 33280, true><<<8192, 512, 0, stream>>>(
      pts, idx, stdv, alpha, beta, nullptr,
      WpPre, b_pre, g_pre, be_pre,
      Wp1a, b1a, g1a, be1a,
      Wp2a, b2a, g2a, be2a,
      pooled1, nullptr);
  k_mlp<8, 264, 33792, false><<<512, 512, 0, stream>>>(
      nullptr, nullptr, nullptr, nullptr, nullptr, pooled1,
      WpPos, b_pos, g_pos, be_pos,
      Wp1b, b1b, g1b, be1b,
      Wp2b, b2b, g2b, be2b,
      nullptr, pooled2);
  k_final<<<1, 512, 0, stream>>>(pooled2, W_fin, b_fin, g_fin, be_fin, (float*)d_out);
}